// Round 7
// baseline (133.575 us; speedup 1.0000x reference)
//
#include <hip/hip_runtime.h>

typedef unsigned long long u64;
typedef unsigned int u32;

#define HH 2048
#define WW 4096
#define MW 66                      // padded row: 1 guard + 64 data + 1 guard
#define MROWS (HH + 20)            // 10 zero guard rows top/bottom
#define MASK_WORDS ((size_t)MROWS * MW)      // 136488
#define MASK_BYTES (MASK_WORDS * 8)
#define THR 10.0f
#define LIST_CAP (512u * 1024u)

#define PACK_BLOCKS 2048
#define COMP_BLOCKS 256            // 128 per image, 1024 words each
#define SCAN_BLOCKS 1024
#define GUARD_WORDS 5416           // 20*66 full guard rows + 2048*2 edge words

// ws layout (bytes):
//      0 : u32 cntP, cntG, done
//    256 : float pn[SCAN_BLOCKS]
//   4352 : float pf[SCAN_BLOCKS]
//  16384 : gmask ; +MASK_BYTES : pmask ; then listP, listG
#define GM_OFF 16384
#define PM_OFF (GM_OFF + MASK_BYTES)
#define LP_OFF (PM_OFF + MASK_BYTES)
#define LG_OFF (LP_OFF + LIST_CAP * 4)

// ------ pack: ballot-pack both images + zero guard words + zero counters -----
__global__ __launch_bounds__(256) void pack_masks(const float* __restrict__ gt,
                                                  const float* __restrict__ pred,
                                                  u64* __restrict__ gm,
                                                  u64* __restrict__ pm,
                                                  u32* __restrict__ cnt) {
    int gtid = blockIdx.x * 256 + threadIdx.x;
    if (gtid < 3) cnt[gtid] = 0u;                    // cntP, cntG, done
    if (gtid < 2 * GUARD_WORDS) {                    // zero guard region
        int m = gtid >= GUARD_WORDS;
        int i = gtid - m * GUARD_WORDS;
        u64* dst = m ? pm : gm;
        int row, w;
        if (i < 660)       { row = i / 66;            w = i - row * 66; }
        else if (i < 1320) { int j = i - 660; int r = j / 66;
                             row = (MROWS - 10) + r;  w = j - r * 66; }
        else               { int j = i - 1320; row = 10 + (j >> 1);
                             w = (j & 1) ? (MW - 1) : 0; }
        dst[(size_t)row * MW + w] = 0ull;
    }

    int l = threadIdx.x & 63;
    int gw = gtid >> 6;                              // 0..8191
    #pragma unroll 1
    for (int t = 0; t < 4; ++t) {
        int tile = gw * 4 + t;                       // 0..32767 (256 px each)
        int base = tile * 256;
        u64 g0 = __ballot(gt[base +   0 + l] > 0.5f);
        u64 g1 = __ballot(gt[base +  64 + l] > 0.5f);
        u64 g2 = __ballot(gt[base + 128 + l] > 0.5f);
        u64 g3 = __ballot(gt[base + 192 + l] > 0.5f);
        u64 p0 = __ballot(pred[base +   0 + l] > 0.5f);
        u64 p1 = __ballot(pred[base +  64 + l] > 0.5f);
        u64 p2 = __ballot(pred[base + 128 + l] > 0.5f);
        u64 p3 = __ballot(pred[base + 192 + l] > 0.5f);
        if (l < 4) {
            u64 gv = (l == 0) ? g0 : (l == 1) ? g1 : (l == 2) ? g2 : g3;
            u64 pv = (l == 0) ? p0 : (l == 1) ? p1 : (l == 2) ? p2 : p3;
            int W = tile * 4 + l;                    // data word 0..131071
            size_t o = (size_t)((W >> 6) + 10) * MW + 1 + (W & 63);
            gm[o] = gv;
            pm[o] = pv;
        }
    }
}

// -------- compact: emit (y<<12|x) for every fg pixel; 1 atomic per block -----
__global__ __launch_bounds__(256) void compact(const u64* __restrict__ gm,
                                               const u64* __restrict__ pm,
                                               u32* __restrict__ cnt,
                                               u32* __restrict__ listP,
                                               u32* __restrict__ listG) {
    bool isPred = blockIdx.x < (COMP_BLOCKS / 2);
    const u64* msk = isPred ? pm : gm;
    u32* lst = isPred ? listP : listG;
    u32* ctr = isPred ? cnt : cnt + 1;
    int wb = (blockIdx.x & (COMP_BLOCKS / 2 - 1)) * 1024;
    int tid = threadIdx.x;

    u64 wv[4];
    u32 tp = 0;
    #pragma unroll
    for (int j = 0; j < 4; ++j) {
        int W = wb + tid + 256 * j;
        wv[j] = msk[(size_t)((W >> 6) + 10) * MW + 1 + (W & 63)];
        tp += (u32)__popcll(wv[j]);
    }
    // wave inclusive scan of tp
    u32 s = tp;
    #pragma unroll
    for (int o = 1; o < 64; o <<= 1) {
        u32 v = __shfl_up(s, o);
        if ((tid & 63) >= o) s += v;
    }
    u32 excl = s - tp;
    __shared__ u32 wtot[4], wbase[4], sbase;
    int wid = tid >> 6, lane = tid & 63;
    if (lane == 63) wtot[wid] = s;
    __syncthreads();
    if (tid == 0) {
        u32 bt = 0;
        for (int i = 0; i < 4; ++i) { wbase[i] = bt; bt += wtot[i]; }
        sbase = atomicAdd(ctr, bt);
    }
    __syncthreads();
    u32 ptr = sbase + wbase[wid] + excl;
    #pragma unroll
    for (int j = 0; j < 4; ++j) {
        int W = wb + tid + 256 * j;
        u32 yx = ((u32)(W >> 6) << 12) | ((u32)(W & 63) << 6);
        u64 m = wv[j];
        while (m) {
            u32 b = (u32)__ffsll((long long)m) - 1u;
            if (ptr < LIST_CAP) lst[ptr] = yx + b;
            ++ptr;
            m &= m - 1;
        }
    }
}

// ---- per-pixel branchless window scan; |dy|<=9 suffices (d2>=100 clamps) ----
__device__ __forceinline__ u32 scan_d2(const u64* __restrict__ rowc, int x) {
    int b = x + 54;                 // window-start bit (pixel x at bit 64+x)
    int sh = b & 63;
    int shl = 63 - sh;
    const u64* q = rowc + (b >> 6);
    u64 q0 = q[0], q1 = q[1];
    u32 win = (u32)((q0 >> sh) | ((q1 << 1) << shl)) & 0x1FFFFFu;
    u32 hi = win >> 10;                       // dx = 0..10
    u32 lo = win & 0x3FFu;                    // dx = -10..-1
    u32 dr = (u32)__ffs((int)hi) - 1u;        // hi==0 -> huge
    u32 dl = (u32)__clz((int)lo) - 21u;       // lo==0 -> 11
    u32 mdx = dr < dl ? dr : dl;
    u32 mind2 = mdx * mdx;
    #pragma unroll
    for (int ady = 1; ady <= 9; ++ady) {
        const u64* r0 = q - (size_t)ady * MW;
        const u64* r1 = q + (size_t)ady * MW;
        u64 a0 = r0[0] | r1[0];
        u64 a1 = r0[1] | r1[1];
        u32 w = (u32)((a0 >> sh) | ((a1 << 1) << shl)) & 0x1FFFFFu;
        u32 h2 = w >> 10;
        u32 l2 = w & 0x3FFu;
        u32 d1 = (u32)__ffs((int)h2) - 1u;
        u32 d0 = (u32)__clz((int)l2) - 21u;
        u32 m2 = d1 < d0 ? d1 : d0;
        u32 d2 = (u32)(ady * ady) + m2 * m2;
        mind2 = d2 < mind2 ? d2 : mind2;
    }
    return mind2;   // >=100 (incl. empty-window 121) all clamp to D=10
}

// ------------- scan + last-block final reduction (fence + ticket) ------------
__global__ __launch_bounds__(256) void dbe_scan(const u64* __restrict__ gm,
                                                const u64* __restrict__ pm,
                                                u32* __restrict__ cnt,
                                                const u32* __restrict__ listP,
                                                const u32* __restrict__ listG,
                                                float* __restrict__ pn,
                                                float* __restrict__ pf,
                                                float* __restrict__ out) {
    u32 cp = cnt[0], cg = cnt[1];
    u32 total = cp + cg;
    float num = 0.0f, filt = 0.0f;

    for (u32 i = blockIdx.x * 256 + threadIdx.x; i < total;
         i += SCAN_BLOCKS * 256) {
        bool isP = i < cp;
        u32 e = isP ? listP[i] : listG[i - cp];
        u32 x = e & 4095u;
        u32 y = e >> 12;
        const u64* base = isP ? gm : pm;     // pred pixel -> dist to gt fg
        u32 d2 = scan_d2(base + (size_t)(y + 10) * MW, (int)x);
        num += fminf(sqrtf((float)d2), THR);
        filt += (isP && d2 < 100u) ? 1.0f : 0.0f;
    }

    #pragma unroll
    for (int o = 32; o > 0; o >>= 1) {
        num += __shfl_down(num, o);
        filt += __shfl_down(filt, o);
    }
    __shared__ float sN[4], sF[4];
    __shared__ u32 ticket;
    int lane = threadIdx.x & 63, wid = threadIdx.x >> 6;
    if (lane == 0) { sN[wid] = num; sF[wid] = filt; }
    __syncthreads();
    if (threadIdx.x == 0) {
        pn[blockIdx.x] = sN[0] + sN[1] + sN[2] + sN[3];
        pf[blockIdx.x] = sF[0] + sF[1] + sF[2] + sF[3];
        __threadfence();                     // release partials
        ticket = atomicAdd(&cnt[2], 1u);
    }
    __syncthreads();
    if (ticket != SCAN_BLOCKS - 1) return;   // uniform per block

    // last block: all other blocks' partials are visible (fence before atomic)
    __threadfence();                         // acquire
    double n = 0.0, f = 0.0;
    for (int i = threadIdx.x; i < SCAN_BLOCKS; i += 256) {
        n += (double)pn[i];
        f += (double)pf[i];
    }
    #pragma unroll
    for (int o = 32; o > 0; o >>= 1) {
        n += __shfl_down(n, o);
        f += __shfl_down(f, o);
    }
    __shared__ double sn[4], sf[4];
    if (lane == 0) { sn[wid] = n; sf[wid] = f; }
    __syncthreads();
    if (threadIdx.x == 0) {
        double N = sn[0] + sn[1] + sn[2] + sn[3];
        double F = sf[0] + sf[1] + sf[2] + sf[3];
        double den = (double)total;          // sum(pred)+sum(gt)
        out[0] = (F == 0.0) ? THR : (float)(N / den);
    }
}

extern "C" void kernel_launch(void* const* d_in, const int* in_sizes, int n_in,
                              void* d_out, int out_size, void* d_ws, size_t ws_size,
                              hipStream_t stream) {
    const float* gt   = (const float*)d_in[0];
    const float* pred = (const float*)d_in[1];
    float* out = (float*)d_out;

    char* ws = (char*)d_ws;
    u32* cnt = (u32*)ws;
    float* pn = (float*)(ws + 256);
    float* pf = (float*)(ws + 4352);
    u64* gm = (u64*)(ws + GM_OFF);
    u64* pm = (u64*)(ws + PM_OFF);
    u32* listP = (u32*)(ws + LP_OFF);
    u32* listG = (u32*)(ws + LG_OFF);

    pack_masks<<<PACK_BLOCKS, 256, 0, stream>>>(gt, pred, gm, pm, cnt);
    compact<<<COMP_BLOCKS, 256, 0, stream>>>(gm, pm, cnt, listP, listG);
    dbe_scan<<<SCAN_BLOCKS, 256, 0, stream>>>(gm, pm, cnt, listP, listG,
                                              pn, pf, out);
}

// Round 8
// 115.961 us; speedup vs baseline: 1.1519x; 1.1519x over previous
//
#include <hip/hip_runtime.h>

typedef unsigned long long u64;
typedef unsigned int u32;

#define HH 2048
#define WW 4096
#define MW 66                      // padded row: 1 guard + 64 data + 1 guard
#define MROWS (HH + 20)            // 10 zero guard rows top/bottom
#define MASK_WORDS ((size_t)MROWS * MW)      // 136488
#define MASK_BYTES (MASK_WORDS * 8)
#define THR 10.0f
#define LIST_CAP (512u * 1024u)

#define PACK_BLOCKS 2048
#define COMP_BLOCKS 256            // 128 per image, 1024 words each
#define SCAN_BLOCKS 1024
#define GUARD_WORDS 5416           // 20*66 full guard rows + 2048*2 edge words

// ws layout (bytes):
//      0 : u32 cntP, cntG
//    256 : float pn[SCAN_BLOCKS]
//   4352 : float pf[SCAN_BLOCKS]
//  16384 : gmask ; +MASK_BYTES : pmask ; then listP, listG
#define GM_OFF 16384
#define PM_OFF (GM_OFF + MASK_BYTES)
#define LP_OFF (PM_OFF + MASK_BYTES)
#define LG_OFF (LP_OFF + LIST_CAP * 4)

// ------ pack: ballot-pack both images + zero guard words + zero counters -----
// Guard-zero threads touch only guard words; ballot path touches only data
// words — disjoint, same kernel, no fence needed.
__global__ __launch_bounds__(256) void pack_masks(const float* __restrict__ gt,
                                                  const float* __restrict__ pred,
                                                  u64* __restrict__ gm,
                                                  u64* __restrict__ pm,
                                                  u32* __restrict__ cnt) {
    int gtid = blockIdx.x * 256 + threadIdx.x;
    if (gtid < 2) cnt[gtid] = 0u;                    // cntP, cntG
    if (gtid < 2 * GUARD_WORDS) {                    // zero guard region
        int m = gtid >= GUARD_WORDS;
        int i = gtid - m * GUARD_WORDS;
        u64* dst = m ? pm : gm;
        int row, w;
        if (i < 660)       { row = i / 66;            w = i - row * 66; }
        else if (i < 1320) { int j = i - 660; int r = j / 66;
                             row = (MROWS - 10) + r;  w = j - r * 66; }
        else               { int j = i - 1320; row = 10 + (j >> 1);
                             w = (j & 1) ? (MW - 1) : 0; }
        dst[(size_t)row * MW + w] = 0ull;
    }

    int l = threadIdx.x & 63;
    int gw = gtid >> 6;                              // 0..8191
    #pragma unroll 1
    for (int t = 0; t < 4; ++t) {
        int tile = gw * 4 + t;                       // 0..32767 (256 px each)
        int base = tile * 256;
        u64 g0 = __ballot(gt[base +   0 + l] > 0.5f);
        u64 g1 = __ballot(gt[base +  64 + l] > 0.5f);
        u64 g2 = __ballot(gt[base + 128 + l] > 0.5f);
        u64 g3 = __ballot(gt[base + 192 + l] > 0.5f);
        u64 p0 = __ballot(pred[base +   0 + l] > 0.5f);
        u64 p1 = __ballot(pred[base +  64 + l] > 0.5f);
        u64 p2 = __ballot(pred[base + 128 + l] > 0.5f);
        u64 p3 = __ballot(pred[base + 192 + l] > 0.5f);
        if (l < 4) {
            u64 gv = (l == 0) ? g0 : (l == 1) ? g1 : (l == 2) ? g2 : g3;
            u64 pv = (l == 0) ? p0 : (l == 1) ? p1 : (l == 2) ? p2 : p3;
            int W = tile * 4 + l;                    // data word 0..131071
            size_t o = (size_t)((W >> 6) + 10) * MW + 1 + (W & 63);
            gm[o] = gv;
            pm[o] = pv;
        }
    }
}

// -------- compact: emit (y<<12|x) for every fg pixel; 1 atomic per block -----
__global__ __launch_bounds__(256) void compact(const u64* __restrict__ gm,
                                               const u64* __restrict__ pm,
                                               u32* __restrict__ cnt,
                                               u32* __restrict__ listP,
                                               u32* __restrict__ listG) {
    bool isPred = blockIdx.x < (COMP_BLOCKS / 2);
    const u64* msk = isPred ? pm : gm;
    u32* lst = isPred ? listP : listG;
    u32* ctr = isPred ? cnt : cnt + 1;
    int wb = (blockIdx.x & (COMP_BLOCKS / 2 - 1)) * 1024;
    int tid = threadIdx.x;

    u64 wv[4];
    u32 tp = 0;
    #pragma unroll
    for (int j = 0; j < 4; ++j) {
        int W = wb + tid + 256 * j;
        wv[j] = msk[(size_t)((W >> 6) + 10) * MW + 1 + (W & 63)];
        tp += (u32)__popcll(wv[j]);
    }
    // wave inclusive scan of tp
    u32 s = tp;
    #pragma unroll
    for (int o = 1; o < 64; o <<= 1) {
        u32 v = __shfl_up(s, o);
        if ((tid & 63) >= o) s += v;
    }
    u32 excl = s - tp;
    __shared__ u32 wtot[4], wbase[4], sbase;
    int wid = tid >> 6, lane = tid & 63;
    if (lane == 63) wtot[wid] = s;
    __syncthreads();
    if (tid == 0) {
        u32 bt = 0;
        for (int i = 0; i < 4; ++i) { wbase[i] = bt; bt += wtot[i]; }
        sbase = atomicAdd(ctr, bt);
    }
    __syncthreads();
    u32 ptr = sbase + wbase[wid] + excl;
    #pragma unroll
    for (int j = 0; j < 4; ++j) {
        int W = wb + tid + 256 * j;
        u32 yx = ((u32)(W >> 6) << 12) | ((u32)(W & 63) << 6);
        u64 m = wv[j];
        while (m) {
            u32 b = (u32)__ffsll((long long)m) - 1u;
            if (ptr < LIST_CAP) lst[ptr] = yx + b;
            ++ptr;
            m &= m - 1;
        }
    }
}

// ---- per-pixel branchless window scan; |dy|<=9 suffices (d2>=100 clamps) ----
__device__ __forceinline__ u32 scan_d2(const u64* __restrict__ rowc, int x) {
    int b = x + 54;                 // window-start bit (pixel x at bit 64+x)
    int sh = b & 63;
    int shl = 63 - sh;
    const u64* q = rowc + (b >> 6);
    u64 q0 = q[0], q1 = q[1];
    u32 win = (u32)((q0 >> sh) | ((q1 << 1) << shl)) & 0x1FFFFFu;
    u32 hi = win >> 10;                       // dx = 0..10
    u32 lo = win & 0x3FFu;                    // dx = -10..-1
    u32 dr = (u32)__ffs((int)hi) - 1u;        // hi==0 -> huge
    u32 dl = (u32)__clz((int)lo) - 21u;       // lo==0 -> 11
    u32 mdx = dr < dl ? dr : dl;
    u32 mind2 = mdx * mdx;
    #pragma unroll
    for (int ady = 1; ady <= 9; ++ady) {
        const u64* r0 = q - (size_t)ady * MW;
        const u64* r1 = q + (size_t)ady * MW;
        u64 a0 = r0[0] | r1[0];
        u64 a1 = r0[1] | r1[1];
        u32 w = (u32)((a0 >> sh) | ((a1 << 1) << shl)) & 0x1FFFFFu;
        u32 h2 = w >> 10;
        u32 l2 = w & 0x3FFu;
        u32 d1 = (u32)__ffs((int)h2) - 1u;
        u32 d0 = (u32)__clz((int)l2) - 21u;
        u32 m2 = d1 < d0 ? d1 : d0;
        u32 d2 = (u32)(ady * ady) + m2 * m2;
        mind2 = d2 < mind2 ? d2 : mind2;
    }
    return mind2;   // >=100 (incl. empty-window 121) all clamp to D=10
}

__global__ __launch_bounds__(256) void dbe_scan(const u64* __restrict__ gm,
                                                const u64* __restrict__ pm,
                                                const u32* __restrict__ cnt,
                                                const u32* __restrict__ listP,
                                                const u32* __restrict__ listG,
                                                float* __restrict__ pn,
                                                float* __restrict__ pf) {
    u32 cp = cnt[0], cg = cnt[1];
    u32 total = cp + cg;
    float num = 0.0f, filt = 0.0f;

    for (u32 i = blockIdx.x * 256 + threadIdx.x; i < total;
         i += SCAN_BLOCKS * 256) {
        bool isP = i < cp;
        u32 e = isP ? listP[i] : listG[i - cp];
        u32 x = e & 4095u;
        u32 y = e >> 12;
        const u64* base = isP ? gm : pm;     // pred pixel -> dist to gt fg
        u32 d2 = scan_d2(base + (size_t)(y + 10) * MW, (int)x);
        num += fminf(sqrtf((float)d2), THR);
        filt += (isP && d2 < 100u) ? 1.0f : 0.0f;
    }

    #pragma unroll
    for (int o = 32; o > 0; o >>= 1) {
        num += __shfl_down(num, o);
        filt += __shfl_down(filt, o);
    }
    __shared__ float sN[4], sF[4];
    int lane = threadIdx.x & 63, wid = threadIdx.x >> 6;
    if (lane == 0) { sN[wid] = num; sF[wid] = filt; }
    __syncthreads();
    if (threadIdx.x == 0) {
        pn[blockIdx.x] = sN[0] + sN[1] + sN[2] + sN[3];
        pf[blockIdx.x] = sF[0] + sF[1] + sF[2] + sF[3];
    }
}

__global__ __launch_bounds__(256) void dbe_reduce(const float* __restrict__ pn,
                                                  const float* __restrict__ pf,
                                                  const u32* __restrict__ cnt,
                                                  float* __restrict__ out) {
    double n = 0.0, f = 0.0;
    for (int i = threadIdx.x; i < SCAN_BLOCKS; i += 256) {
        n += (double)pn[i];
        f += (double)pf[i];
    }
    #pragma unroll
    for (int o = 32; o > 0; o >>= 1) {
        n += __shfl_down(n, o);
        f += __shfl_down(f, o);
    }
    __shared__ double sn[4], sf[4];
    int lane = threadIdx.x & 63, wid = threadIdx.x >> 6;
    if (lane == 0) { sn[wid] = n; sf[wid] = f; }
    __syncthreads();
    if (threadIdx.x == 0) {
        double N = sn[0] + sn[1] + sn[2] + sn[3];
        double F = sf[0] + sf[1] + sf[2] + sf[3];
        double den = (double)(cnt[0] + cnt[1]);   // sum(pred)+sum(gt)
        out[0] = (F == 0.0) ? THR : (float)(N / den);
    }
}

extern "C" void kernel_launch(void* const* d_in, const int* in_sizes, int n_in,
                              void* d_out, int out_size, void* d_ws, size_t ws_size,
                              hipStream_t stream) {
    const float* gt   = (const float*)d_in[0];
    const float* pred = (const float*)d_in[1];
    float* out = (float*)d_out;

    char* ws = (char*)d_ws;
    u32* cnt = (u32*)ws;
    float* pn = (float*)(ws + 256);
    float* pf = (float*)(ws + 4352);
    u64* gm = (u64*)(ws + GM_OFF);
    u64* pm = (u64*)(ws + PM_OFF);
    u32* listP = (u32*)(ws + LP_OFF);
    u32* listG = (u32*)(ws + LG_OFF);

    pack_masks<<<PACK_BLOCKS, 256, 0, stream>>>(gt, pred, gm, pm, cnt);
    compact<<<COMP_BLOCKS, 256, 0, stream>>>(gm, pm, cnt, listP, listG);
    dbe_scan<<<SCAN_BLOCKS, 256, 0, stream>>>(gm, pm, cnt, listP, listG, pn, pf);
    dbe_reduce<<<1, 256, 0, stream>>>(pn, pf, cnt, out);
}

// Round 9
// 107.896 us; speedup vs baseline: 1.2380x; 1.0748x over previous
//
#include <hip/hip_runtime.h>

typedef unsigned long long u64;
typedef unsigned int u32;

#define HH 2048
#define WW 4096
#define MW 66                      // padded row: 1 guard + 64 data + 1 guard
#define MROWS (HH + 20)            // 10 zero guard rows top/bottom
#define MASK_WORDS ((size_t)MROWS * MW)      // 136488
#define MASK_BYTES (MASK_WORDS * 8)
#define THR 10.0f

#define FUSED_BLOCKS 1024          // 4 waves/block, 32 words/wave/image
#define SCAN_BLOCKS  1024          // scan block b <-> pack block b's segment
#define SEG 2048                   // entries per block per list (expect ~410)
#define GUARD_WORDS 5416           // 20*66 full guard rows + 2048*2 edge words

// ws layout (bytes) — nothing needs pre-zeroing:
//      0 : u32 cntPb[1024]
//   4096 : u32 cntGb[1024]
//   8192 : float pn[1024]
//  12288 : float pf[1024]
//  16384 : gmask ; +MASK_BYTES : pmask ; then listP, listG (SEG*1024 u32 each)
#define GM_OFF 16384
#define PM_OFF (GM_OFF + MASK_BYTES)
#define LP_OFF (PM_OFF + MASK_BYTES)
#define LG_OFF (LP_OFF + (size_t)SEG * FUSED_BLOCKS * 4)

// --- fused: ballot-pack masks + guard-zero + per-block compact (no atomics) --
// Wave owns 32 consecutive words per image; lane l<32 keeps gword[wbase+l],
// lane l>=32 keeps pword[wbase+l-32]. Emission goes to the block's private
// segment, so no cross-block coordination exists anywhere.
__global__ __launch_bounds__(256) void pack_compact(const float* __restrict__ gt,
                                                    const float* __restrict__ pred,
                                                    u64* __restrict__ gm,
                                                    u64* __restrict__ pm,
                                                    u32* __restrict__ cntPb,
                                                    u32* __restrict__ cntGb,
                                                    u32* __restrict__ listP,
                                                    u32* __restrict__ listG) {
    int tid = threadIdx.x;
    int l = tid & 63;
    int wv = tid >> 6;                         // wave 0..3
    int b = blockIdx.x;

    // zero guard words (blocks 0..42 only; guards never read in this kernel)
    int gtid = b * 256 + tid;
    if (gtid < 2 * GUARD_WORDS) {
        int m = gtid >= GUARD_WORDS;
        int i = gtid - m * GUARD_WORDS;
        u64* dst = m ? pm : gm;
        int row, w;
        if (i < 660)       { row = i / 66;            w = i - row * 66; }
        else if (i < 1320) { int j = i - 660; int r = j / 66;
                             row = (MROWS - 10) + r;  w = j - r * 66; }
        else               { int j = i - 1320; row = 10 + (j >> 1);
                             w = (j & 1) ? (MW - 1) : 0; }
        dst[(size_t)row * MW + w] = 0ull;
    }

    int wbase = b * 128 + wv * 32;             // wave's first word index
    int idx = (l < 32) ? l : (l - 32);
    u64 myw = 0;
    #pragma unroll 1
    for (int t = 0; t < 8; ++t) {
        int w0 = wbase + 4 * t;
        size_t px = (size_t)w0 * 64 + l;
        u64 g0 = __ballot(gt[px +   0] > 0.5f);
        u64 g1 = __ballot(gt[px +  64] > 0.5f);
        u64 g2 = __ballot(gt[px + 128] > 0.5f);
        u64 g3 = __ballot(gt[px + 192] > 0.5f);
        u64 p0 = __ballot(pred[px +   0] > 0.5f);
        u64 p1 = __ballot(pred[px +  64] > 0.5f);
        u64 p2 = __ballot(pred[px + 128] > 0.5f);
        u64 p3 = __ballot(pred[px + 192] > 0.5f);
        if ((idx >> 2) == t) {                 // this lane's word is in tile t
            int j = idx & 3;
            u64 gsel = (j == 0) ? g0 : (j == 1) ? g1 : (j == 2) ? g2 : g3;
            u64 psel = (j == 0) ? p0 : (j == 1) ? p1 : (j == 2) ? p2 : p3;
            myw = (l < 32) ? gsel : psel;
        }
    }

    int myW = wbase + idx;                     // word 0..131071
    size_t o = (size_t)((myW >> 6) + 10) * MW + 1 + (myW & 63);
    if (l < 32) gm[o] = myw; else pm[o] = myw;

    // wave inclusive scan of popcounts (G lanes 0..31 precede P lanes 32..63)
    u32 pc = (u32)__popcll(myw);
    u32 s = pc;
    #pragma unroll
    for (int off = 1; off < 64; off <<= 1) {
        u32 v = __shfl_up(s, off);
        if (l >= off) s += v;
    }
    u32 excl = s - pc;
    u32 gtot = __shfl(s, 31);                  // wave's G total
    u32 tot  = __shfl(s, 63);
    u32 ptot = tot - gtot;

    __shared__ u32 wg[4], wp[4];
    if (l == 0) { wg[wv] = gtot; wp[wv] = ptot; }
    __syncthreads();
    u32 gbase = 0, pbase = 0;
    #pragma unroll
    for (int i = 0; i < 4; ++i) {
        gbase += (i < wv) ? wg[i] : 0u;
        pbase += (i < wv) ? wp[i] : 0u;
    }
    if (tid == 0) {
        cntGb[b] = wg[0] + wg[1] + wg[2] + wg[3];
        cntPb[b] = wp[0] + wp[1] + wp[2] + wp[3];
    }

    u32 ptr = (l < 32) ? (gbase + excl) : (pbase + (excl - gtot));
    u32* lst = ((l < 32) ? listG : listP) + (size_t)b * SEG;
    u32 e0 = (u32)myW << 6;                    // == (y<<12)|(x&~63)
    u64 m = myw;
    while (m) {
        u32 bit = (u32)__ffsll((long long)m) - 1u;
        lst[ptr++] = e0 + bit;
        m &= m - 1;
    }
}

// ---- per-pixel branchless window scan; |dy|<=9 suffices (d2>=100 clamps) ----
__device__ __forceinline__ u32 scan_d2(const u64* __restrict__ rowc, int x) {
    int b = x + 54;                 // window-start bit (pixel x at bit 64+x)
    int sh = b & 63;
    int shl = 63 - sh;
    const u64* q = rowc + (b >> 6);
    u64 q0 = q[0], q1 = q[1];
    u32 win = (u32)((q0 >> sh) | ((q1 << 1) << shl)) & 0x1FFFFFu;
    u32 hi = win >> 10;                       // dx = 0..10
    u32 lo = win & 0x3FFu;                    // dx = -10..-1
    u32 dr = (u32)__ffs((int)hi) - 1u;        // hi==0 -> huge
    u32 dl = (u32)__clz((int)lo) - 21u;       // lo==0 -> 11
    u32 mdx = dr < dl ? dr : dl;
    u32 mind2 = mdx * mdx;
    #pragma unroll
    for (int ady = 1; ady <= 9; ++ady) {
        const u64* r0 = q - (size_t)ady * MW;
        const u64* r1 = q + (size_t)ady * MW;
        u64 a0 = r0[0] | r1[0];
        u64 a1 = r0[1] | r1[1];
        u32 w = (u32)((a0 >> sh) | ((a1 << 1) << shl)) & 0x1FFFFFu;
        u32 h2 = w >> 10;
        u32 l2 = w & 0x3FFu;
        u32 d1 = (u32)__ffs((int)h2) - 1u;
        u32 d0 = (u32)__clz((int)l2) - 21u;
        u32 m2 = d1 < d0 ? d1 : d0;
        u32 d2 = (u32)(ady * ady) + m2 * m2;
        mind2 = d2 < mind2 ? d2 : mind2;
    }
    return mind2;   // >=100 (incl. empty-window 121) all clamp to D=10
}

// ---------------- scan: block b processes pack block b's segment -------------
__global__ __launch_bounds__(256) void dbe_scan(const u64* __restrict__ gm,
                                                const u64* __restrict__ pm,
                                                const u32* __restrict__ cntPb,
                                                const u32* __restrict__ cntGb,
                                                const u32* __restrict__ listP,
                                                const u32* __restrict__ listG,
                                                float* __restrict__ pn,
                                                float* __restrict__ pf) {
    int b = blockIdx.x;
    u32 cp = cntPb[b], cg = cntGb[b];
    u32 total = cp + cg;
    const u32* segP = listP + (size_t)b * SEG;
    const u32* segG = listG + (size_t)b * SEG;
    float num = 0.0f, filt = 0.0f;

    for (u32 i = threadIdx.x; i < total; i += 256) {
        bool isP = i < cp;
        u32 e = isP ? segP[i] : segG[i - cp];
        u32 x = e & 4095u;
        u32 y = e >> 12;
        const u64* base = isP ? gm : pm;     // pred pixel -> dist to gt fg
        u32 d2 = scan_d2(base + (size_t)(y + 10) * MW, (int)x);
        num += fminf(sqrtf((float)d2), THR);
        filt += (isP && d2 < 100u) ? 1.0f : 0.0f;
    }

    #pragma unroll
    for (int o = 32; o > 0; o >>= 1) {
        num += __shfl_down(num, o);
        filt += __shfl_down(filt, o);
    }
    __shared__ float sN[4], sF[4];
    int lane = threadIdx.x & 63, wid = threadIdx.x >> 6;
    if (lane == 0) { sN[wid] = num; sF[wid] = filt; }
    __syncthreads();
    if (threadIdx.x == 0) {
        pn[b] = sN[0] + sN[1] + sN[2] + sN[3];
        pf[b] = sF[0] + sF[1] + sF[2] + sF[3];
    }
}

__global__ __launch_bounds__(256) void dbe_reduce(const float* __restrict__ pn,
                                                  const float* __restrict__ pf,
                                                  const u32* __restrict__ cntPb,
                                                  const u32* __restrict__ cntGb,
                                                  float* __restrict__ out) {
    double n = 0.0, f = 0.0;
    u32 c = 0;
    for (int i = threadIdx.x; i < SCAN_BLOCKS; i += 256) {
        n += (double)pn[i];
        f += (double)pf[i];
        c += cntPb[i] + cntGb[i];
    }
    #pragma unroll
    for (int o = 32; o > 0; o >>= 1) {
        n += __shfl_down(n, o);
        f += __shfl_down(f, o);
        c += __shfl_down(c, o);
    }
    __shared__ double sn[4], sf[4];
    __shared__ u32 sc[4];
    int lane = threadIdx.x & 63, wid = threadIdx.x >> 6;
    if (lane == 0) { sn[wid] = n; sf[wid] = f; sc[wid] = c; }
    __syncthreads();
    if (threadIdx.x == 0) {
        double N = sn[0] + sn[1] + sn[2] + sn[3];
        double F = sf[0] + sf[1] + sf[2] + sf[3];
        double den = (double)(sc[0] + sc[1] + sc[2] + sc[3]);
        out[0] = (F == 0.0) ? THR : (float)(N / den);
    }
}

extern "C" void kernel_launch(void* const* d_in, const int* in_sizes, int n_in,
                              void* d_out, int out_size, void* d_ws, size_t ws_size,
                              hipStream_t stream) {
    const float* gt   = (const float*)d_in[0];
    const float* pred = (const float*)d_in[1];
    float* out = (float*)d_out;

    char* ws = (char*)d_ws;
    u32* cntPb = (u32*)ws;
    u32* cntGb = (u32*)(ws + 4096);
    float* pn = (float*)(ws + 8192);
    float* pf = (float*)(ws + 12288);
    u64* gm = (u64*)(ws + GM_OFF);
    u64* pm = (u64*)(ws + PM_OFF);
    u32* listP = (u32*)(ws + LP_OFF);
    u32* listG = (u32*)(ws + LG_OFF);

    pack_compact<<<FUSED_BLOCKS, 256, 0, stream>>>(gt, pred, gm, pm,
                                                   cntPb, cntGb, listP, listG);
    dbe_scan<<<SCAN_BLOCKS, 256, 0, stream>>>(gm, pm, cntPb, cntGb,
                                              listP, listG, pn, pf);
    dbe_reduce<<<1, 256, 0, stream>>>(pn, pf, cntPb, cntGb, out);
}